// Round 4
// baseline (718.533 us; speedup 1.0000x reference)
//
#include <hip/hip_runtime.h>
#include <math.h>

#define B_ 256
#define A_ 196
#define R_ 1024
#define V_ 10000
#define G4 4096
#define M_ (B_ * A_)   // 50176

typedef __bf16 bf16x8 __attribute__((ext_vector_type(8)));
typedef float f32x4 __attribute__((ext_vector_type(4)));

// ws layout in floats (~46.5 MB)
#define OFF_ATTH   0
#define OFF_SCORE  50176
#define OFF_WEIGHT 100352
#define OFF_ATTRES 150528
#define OFF_P0     412672
#define OFF_P1     1461248
#define OFF_P2     2509824
#define OFF_NHBF   3558400
#define OFF_LOGITS 3689472
#define OFF_PACKA  6249472   // a2a_w bf16 [208][1024]
#define OFF_PACKH  6355968   // h2a_w bf16 [256][1024]
#define OFF_PACKP  6487040   // proj_w bf16 [10048][1024]

__device__ __forceinline__ float tanh_fast(float x) {
    float e = __expf(2.f * x);
    return 1.f - 2.f / (e + 1.f);
}
__device__ __forceinline__ float sigmoid_fast(float x) {
    return 1.f / (1.f + __expf(-x));
}

__device__ __forceinline__ bf16x8 cvt8(float4 f0, float4 f1) {
    bf16x8 v;
    v[0] = (__bf16)f0.x; v[1] = (__bf16)f0.y; v[2] = (__bf16)f0.z; v[3] = (__bf16)f0.w;
    v[4] = (__bf16)f1.x; v[5] = (__bf16)f1.y; v[6] = (__bf16)f1.z; v[7] = (__bf16)f1.w;
    return v;
}

// ---------------- kernel 0: pack a2a_w, h2a_w, proj_w to bf16 (zero-padded) ---
__global__ void pack_kernel(const float* __restrict__ a2a_w,
                            const float* __restrict__ h2a_w,
                            const float* __restrict__ proj_w,
                            __bf16* __restrict__ packA,   // [208][1024]
                            __bf16* __restrict__ packH,   // [256][1024]
                            __bf16* __restrict__ packP) { // [10048][1024]
    int row = blockIdx.x;
    int c = threadIdx.x * 4;
    const float* src;
    __bf16* dst;
    if (row < 208) {
        src = (row < A_) ? a2a_w + (size_t)row * R_ + c : nullptr;
        dst = packA + (size_t)row * R_ + c;
    } else if (row < 464) {
        int r2 = row - 208;
        src = (r2 < A_) ? h2a_w + (size_t)r2 * R_ + c : nullptr;
        dst = packH + (size_t)r2 * R_ + c;
    } else {
        int r3 = row - 464;
        src = (r3 < V_) ? proj_w + (size_t)r3 * R_ + c : nullptr;
        dst = packP + (size_t)r3 * R_ + c;
    }
    float4 f = src ? *(const float4*)src : make_float4(0.f, 0.f, 0.f, 0.f);
    dst[0] = (__bf16)f.x; dst[1] = (__bf16)f.y; dst[2] = (__bf16)f.z; dst[3] = (__bf16)f.w;
}

// ---------------- kernel 1: att_h = prev_h @ h2a_w.T + h2a_b  (MFMA) ----------
__global__ __launch_bounds__(256)
void att_h_gemm(const float* __restrict__ prev_h,
                const __bf16* __restrict__ packH,
                const float* __restrict__ h2a_b,
                float* __restrict__ att_h) {
    __shared__ alignas(16) __bf16 As[64][40];
    __shared__ alignas(16) __bf16 Bs[64][40];
    int tid = threadIdx.x;
    int m0 = blockIdx.x * 64, n0 = blockIdx.y * 64;
    int lane = tid & 63, w = tid >> 6, ln = lane & 15, quad = lane >> 4;
    int arow = tid >> 2, akq = (tid & 3) * 8;

    f32x4 acc[4];
#pragma unroll
    for (int t = 0; t < 4; ++t) acc[t] = {0.f, 0.f, 0.f, 0.f};

    const float* Asrc = prev_h + (size_t)(m0 + arow) * R_ + akq;
    const __bf16* Bsrc = packH + (size_t)(n0 + arow) * R_ + akq;

    float4 pa0 = *(const float4*)Asrc;
    float4 pa1 = *(const float4*)(Asrc + 4);
    bf16x8 pb = *(const bf16x8*)Bsrc;

    for (int k0 = 0; k0 < R_; k0 += 32) {
        __syncthreads();
        *(bf16x8*)&As[arow][akq] = cvt8(pa0, pa1);
        *(bf16x8*)&Bs[arow][akq] = pb;
        __syncthreads();
        if (k0 + 32 < R_) {
            pa0 = *(const float4*)(Asrc + k0 + 32);
            pa1 = *(const float4*)(Asrc + k0 + 36);
            pb = *(const bf16x8*)(Bsrc + k0 + 32);
        }
        bf16x8 a = *(bf16x8*)&As[w * 16 + ln][quad * 8];
#pragma unroll
        for (int t = 0; t < 4; ++t) {
            bf16x8 b = *(bf16x8*)&Bs[t * 16 + ln][quad * 8];
            acc[t] = __builtin_amdgcn_mfma_f32_16x16x32_bf16(a, b, acc[t], 0, 0, 0);
        }
    }
#pragma unroll
    for (int t = 0; t < 4; ++t) {
#pragma unroll
        for (int r = 0; r < 4; ++r) {
            int m = m0 + w * 16 + quad * 4 + r;
            int n = n0 + t * 16 + ln;
            if (n < A_) att_h[m * A_ + n] = acc[t][r] + h2a_b[n];
        }
    }
}

// ---------------- kernel 2: attention GEMM (MFMA) + tanh/d2d epilogue ---------
// BM=64; waves split N (tiles 4/3/3/3), each wave m-unrolled x4.
// Depth-2 A prefetch (HBM), depth-1 B prefetch (L2).
__global__ __launch_bounds__(256)
void score_gemm_mfma(const float* __restrict__ att,
                     const __bf16* __restrict__ packA,
                     const float* __restrict__ a2a_b,
                     const float* __restrict__ d2d_w,
                     const float* __restrict__ att_h,
                     float* __restrict__ score) {
    __shared__ alignas(16) __bf16 As[64][40];
    __shared__ alignas(16) __bf16 Bs[208][40];
    __shared__ float sred[4][64];
    int tid = threadIdx.x;
    int m0 = blockIdx.x * 64;
    int lane = tid & 63, w = tid >> 6, ln = lane & 15, quad = lane >> 4;
    int arow = tid >> 2, akq = (tid & 3) * 8;
    int nstart = (w == 0) ? 0 : 3 * w + 1;
    int ncnt = (w == 0) ? 4 : 3;

    f32x4 acc[4][4];
#pragma unroll
    for (int mt = 0; mt < 4; ++mt)
#pragma unroll
        for (int t = 0; t < 4; ++t) acc[mt][t] = {0.f, 0.f, 0.f, 0.f};

    const float* Asrc = att + (size_t)(m0 + arow) * R_ + akq;
    const __bf16* Bb = packA + (size_t)arow * R_ + akq;

    // A depth-2, B depth-1. Thread's B rows: arow, arow+64, arow+128, (arow<16: +192)
    float4 pa0[2], pa1[2];
    pa0[0] = *(const float4*)(Asrc);      pa1[0] = *(const float4*)(Asrc + 4);
    pa0[1] = *(const float4*)(Asrc + 32); pa1[1] = *(const float4*)(Asrc + 36);
    bf16x8 pbv[4];
#pragma unroll
    for (int i = 0; i < 4; ++i)
        if (i < 3 || arow < 16) pbv[i] = *(const bf16x8*)(Bb + (size_t)i * 64 * R_);

    for (int it = 0; it < 32; ++it) {
        int k0 = it * 32;
        int p = it & 1;
        __syncthreads();
        *(bf16x8*)&As[arow][akq] = cvt8(pa0[p], pa1[p]);
        *(bf16x8*)&Bs[arow][akq] = pbv[0];
        *(bf16x8*)&Bs[arow + 64][akq] = pbv[1];
        *(bf16x8*)&Bs[arow + 128][akq] = pbv[2];
        if (arow < 16) *(bf16x8*)&Bs[arow + 192][akq] = pbv[3];
        __syncthreads();
        if (k0 + 64 < R_) {
            pa0[p] = *(const float4*)(Asrc + k0 + 64);
            pa1[p] = *(const float4*)(Asrc + k0 + 68);
        }
        if (k0 + 32 < R_) {
#pragma unroll
            for (int i = 0; i < 4; ++i)
                if (i < 3 || arow < 16)
                    pbv[i] = *(const bf16x8*)(Bb + (size_t)i * 64 * R_ + k0 + 32);
        }
        bf16x8 af[4];
#pragma unroll
        for (int mt = 0; mt < 4; ++mt) af[mt] = *(bf16x8*)&As[mt * 16 + ln][quad * 8];
#pragma unroll
        for (int t = 0; t < 4; ++t) {
            if (t < ncnt) {
                bf16x8 b = *(bf16x8*)&Bs[(nstart + t) * 16 + ln][quad * 8];
#pragma unroll
                for (int mt = 0; mt < 4; ++mt)
                    acc[mt][t] = __builtin_amdgcn_mfma_f32_16x16x32_bf16(af[mt], b, acc[mt][t], 0, 0, 0);
            }
        }
    }

    float wv[4], bb[4];
#pragma unroll
    for (int t = 0; t < 4; ++t) {
        int n = (nstart + t) * 16 + ln;
        bool v = (t < ncnt) && (n < A_);
        wv[t] = v ? d2d_w[n] : 0.f;
        bb[t] = v ? a2a_b[n] : 0.f;
    }
#pragma unroll
    for (int mt = 0; mt < 4; ++mt) {
#pragma unroll
        for (int r = 0; r < 4; ++r) {
            int row = mt * 16 + quad * 4 + r;
            float ah = att_h[m0 + row];
            float pp = 0.f;
#pragma unroll
            for (int t = 0; t < 4; ++t)
                if (t < ncnt) pp += tanh_fast(acc[mt][t][r] + bb[t] + ah) * wv[t];
            pp += __shfl_xor(pp, 1);
            pp += __shfl_xor(pp, 2);
            pp += __shfl_xor(pp, 4);
            pp += __shfl_xor(pp, 8);
            if (ln == 0) sred[w][row] = pp;
        }
    }
    __syncthreads();
    if (tid < 64) score[m0 + tid] = sred[0][tid] + sred[1][tid] + sred[2][tid] + sred[3][tid];
}

// ---------------- kernel 3: softmax over i per batch ---------------------------
__global__ void softmax_kernel(const float* __restrict__ score,
                               const float* __restrict__ d2d_b,
                               float* __restrict__ weight) {
    int b = blockIdx.x;
    int i = threadIdx.x;
    __shared__ float red[256];
    float sval = 0.f;
    float s = -1e30f;
    if (i < A_) {
        sval = score[b * A_ + i] + d2d_b[0];
        s = sval;
    }
    red[i] = s; __syncthreads();
    for (int off = 128; off > 0; off >>= 1) {
        if (i < off) red[i] = fmaxf(red[i], red[i + off]);
        __syncthreads();
    }
    float mx = red[0]; __syncthreads();
    float e = (i < A_) ? __expf(sval - mx) : 0.f;
    red[i] = e; __syncthreads();
    for (int off = 128; off > 0; off >>= 1) {
        if (i < off) red[i] += red[i + off];
        __syncthreads();
    }
    float inv = 1.f / red[0];
    if (i < A_) weight[b * A_ + i] = e * inv;
}

// ---------------- kernel 4: att_res += partial over i-quarter (atomic) --------
__global__ __launch_bounds__(256)
void att_res_kernel(const float* __restrict__ att,
                    const float* __restrict__ weight,
                    float* __restrict__ att_res) {
    int b = blockIdx.x;
    int seg = blockIdx.y;          // 4 segments of 49 rows
    int r = threadIdx.x * 4;
    __shared__ float w[49];
    int i0 = seg * 49;
    if (threadIdx.x < 49) w[threadIdx.x] = weight[b * A_ + i0 + threadIdx.x];
    __syncthreads();
    const float* ap = att + ((size_t)b * A_ + i0) * R_ + r;
    float4 acc = make_float4(0.f, 0.f, 0.f, 0.f);
    for (int i = 0; i < 49; i += 7) {
#pragma unroll
        for (int j = 0; j < 7; ++j) {
            float4 v = *(const float4*)(ap + (size_t)(i + j) * R_);
            float ww = w[i + j];
            acc.x += v.x * ww; acc.y += v.y * ww;
            acc.z += v.z * ww; acc.w += v.w * ww;
        }
    }
    float* dst = att_res + (size_t)b * R_ + r;
    atomicAdd(dst + 0, acc.x);
    atomicAdd(dst + 1, acc.y);
    atomicAdd(dst + 2, acc.z);
    atomicAdd(dst + 3, acc.w);
}

// ---------------- kernel 5: sums GEMM (MFMA, phase-split z=3) ------------------
__global__ __launch_bounds__(256)
void sums_gemm_mfma(const float* __restrict__ x,
                    const float* __restrict__ prev_h,
                    const float* __restrict__ att_res,
                    const float* __restrict__ i2h_w,
                    const float* __restrict__ h2h_w,
                    const float* __restrict__ r2a_w,
                    float* __restrict__ P0,
                    float* __restrict__ P1,
                    float* __restrict__ P2) {
    __shared__ alignas(16) __bf16 As[64][40];
    __shared__ alignas(16) __bf16 Bs[64][40];
    int tid = threadIdx.x;
    int m0 = blockIdx.x * 64, n0 = blockIdx.y * 64;
    int z = blockIdx.z;
    int lane = tid & 63, w = tid >> 6, ln = lane & 15, quad = lane >> 4;
    int arow = tid >> 2, akq = (tid & 3) * 8;

    f32x4 acc[4];
#pragma unroll
    for (int t = 0; t < 4; ++t) acc[t] = {0.f, 0.f, 0.f, 0.f};

    const float* Al[3] = {x, prev_h, att_res};
    const float* Bl[3] = {i2h_w, h2h_w, r2a_w};
    float* Pl[3] = {P0, P1, P2};
    const float* Asrc = Al[z] + (size_t)(m0 + arow) * R_ + akq;
    const float* Bsrc = Bl[z] + (size_t)(n0 + arow) * R_ + akq;

    float4 pa0 = *(const float4*)Asrc;
    float4 pa1 = *(const float4*)(Asrc + 4);
    float4 pb0 = *(const float4*)Bsrc;
    float4 pb1 = *(const float4*)(Bsrc + 4);
    for (int k0 = 0; k0 < R_; k0 += 32) {
        __syncthreads();
        *(bf16x8*)&As[arow][akq] = cvt8(pa0, pa1);
        *(bf16x8*)&Bs[arow][akq] = cvt8(pb0, pb1);
        __syncthreads();
        if (k0 + 32 < R_) {
            pa0 = *(const float4*)(Asrc + k0 + 32);
            pa1 = *(const float4*)(Asrc + k0 + 36);
            pb0 = *(const float4*)(Bsrc + k0 + 32);
            pb1 = *(const float4*)(Bsrc + k0 + 36);
        }
        bf16x8 a = *(bf16x8*)&As[w * 16 + ln][quad * 8];
#pragma unroll
        for (int t = 0; t < 4; ++t) {
            bf16x8 b = *(bf16x8*)&Bs[t * 16 + ln][quad * 8];
            acc[t] = __builtin_amdgcn_mfma_f32_16x16x32_bf16(a, b, acc[t], 0, 0, 0);
        }
    }
    float* P = Pl[z];
#pragma unroll
    for (int t = 0; t < 4; ++t) {
#pragma unroll
        for (int r = 0; r < 4; ++r) {
            int m = m0 + w * 16 + quad * 4 + r;
            int n = n0 + t * 16 + ln;
            P[(size_t)m * G4 + n] = acc[t][r];
        }
    }
}

// ---------------- kernel 6: LSTM gates ----------------------------------------
__global__ void gates_kernel(const float* __restrict__ P0,
                             const float* __restrict__ P1,
                             const float* __restrict__ P2,
                             const float* __restrict__ i2h_b,
                             const float* __restrict__ h2h_b,
                             const float* __restrict__ r2a_b,
                             const float* __restrict__ prev_c,
                             float* __restrict__ out_c,
                             float* __restrict__ out_h,
                             __bf16* __restrict__ nh_bf) {
    int idx = blockIdx.x * 256 + threadIdx.x;
    int b = idx >> 10, r = idx & 1023;
    size_t off = (size_t)b * G4;
    float s0 = P0[off + r] + P1[off + r] + P2[off + r]
             + i2h_b[r] + h2h_b[r] + r2a_b[r];
    float s1 = P0[off + R_ + r] + P1[off + R_ + r] + P2[off + R_ + r]
             + i2h_b[R_ + r] + h2h_b[R_ + r] + r2a_b[R_ + r];
    float s2 = P0[off + 2 * R_ + r] + P1[off + 2 * R_ + r] + P2[off + 2 * R_ + r]
             + i2h_b[2 * R_ + r] + h2h_b[2 * R_ + r] + r2a_b[2 * R_ + r];
    float s3 = P0[off + 3 * R_ + r] + P1[off + 3 * R_ + r] + P2[off + 3 * R_ + r]
             + i2h_b[3 * R_ + r] + h2h_b[3 * R_ + r] + r2a_b[3 * R_ + r];
    float ig = sigmoid_fast(s0);
    float fg = sigmoid_fast(s1);
    float og = sigmoid_fast(s2);
    float it = tanh_fast(s3);
    float nc = fg * prev_c[idx] + ig * it;
    float nh = og * tanh_fast(nc);
    out_c[idx] = nc;
    out_h[idx] = nh;
    nh_bf[idx] = (__bf16)nh;
}

// ---------------- kernel 7: proj GEMM (MFMA, bf16 B, depth-2 B prefetch) ------
__global__ __launch_bounds__(256)
void proj_gemm_mfma(const __bf16* __restrict__ nh_bf,
                    const __bf16* __restrict__ packP,
                    const float* __restrict__ proj_b,
                    float* __restrict__ logits) {
    __shared__ alignas(16) __bf16 As[64][40];
    __shared__ alignas(16) __bf16 Bs[64][40];
    int tid = threadIdx.x;
    int m0 = blockIdx.x * 64, n0 = blockIdx.y * 64;
    int lane = tid & 63, w = tid >> 6, ln = lane & 15, quad = lane >> 4;
    int arow = tid >> 2, akq = (tid & 3) * 8;

    f32x4 acc[4];
#pragma unroll
    for (int t = 0; t < 4; ++t) acc[t] = {0.f, 0.f, 0.f, 0.f};

    const __bf16* Asrc = nh_bf + (size_t)(m0 + arow) * R_ + akq;
    const __bf16* Bsrc = packP + (size_t)(n0 + arow) * R_ + akq;

    bf16x8 pa = *(const bf16x8*)Asrc;
    bf16x8 pb[2];
    pb[0] = *(const bf16x8*)Bsrc;
    pb[1] = *(const bf16x8*)(Bsrc + 32);

    for (int it = 0; it < 32; ++it) {
        int k0 = it * 32;
        int p = it & 1;
        __syncthreads();
        *(bf16x8*)&As[arow][akq] = pa;
        *(bf16x8*)&Bs[arow][akq] = pb[p];
        __syncthreads();
        if (k0 + 32 < R_) pa = *(const bf16x8*)(Asrc + k0 + 32);
        if (k0 + 64 < R_) pb[p] = *(const bf16x8*)(Bsrc + k0 + 64);
        bf16x8 a = *(bf16x8*)&As[w * 16 + ln][quad * 8];
#pragma unroll
        for (int t = 0; t < 4; ++t) {
            bf16x8 b = *(bf16x8*)&Bs[t * 16 + ln][quad * 8];
            acc[t] = __builtin_amdgcn_mfma_f32_16x16x32_bf16(a, b, acc[t], 0, 0, 0);
        }
    }
#pragma unroll
    for (int t = 0; t < 4; ++t) {
#pragma unroll
        for (int r = 0; r < 4; ++r) {
            int m = m0 + w * 16 + quad * 4 + r;
            int n = n0 + t * 16 + ln;
            if (n < V_) logits[(size_t)m * V_ + n] = acc[t][r] + proj_b[n];
        }
    }
}

// ---------------- kernel 8: log_softmax over V per row (1024 threads) ----------
__global__ __launch_bounds__(1024)
void logsoftmax_kernel(const float* __restrict__ logits,
                       float* __restrict__ out) {
    int b = blockIdx.x, t = threadIdx.x;
    __shared__ float red[1024];
    const float* lp = logits + (size_t)b * V_;
    float mx = -1e30f;
    for (int v = t; v < V_; v += 1024) mx = fmaxf(mx, lp[v]);
    red[t] = mx; __syncthreads();
    for (int off = 512; off > 0; off >>= 1) {
        if (t < off) red[t] = fmaxf(red[t], red[t + off]);
        __syncthreads();
    }
    mx = red[0]; __syncthreads();
    float s = 0.f;
    for (int v = t; v < V_; v += 1024) s += __expf(lp[v] - mx);
    red[t] = s; __syncthreads();
    for (int off = 512; off > 0; off >>= 1) {
        if (t < off) red[t] += red[t + off];
        __syncthreads();
    }
    float lse = mx + __logf(red[0]);
    float* op = out + (size_t)b * V_;
    for (int v = t; v < V_; v += 1024) op[v] = lp[v] - lse;
}

extern "C" void kernel_launch(void* const* d_in, const int* in_sizes, int n_in,
                              void* d_out, int out_size, void* d_ws, size_t ws_size,
                              hipStream_t stream) {
    const float* x      = (const float*)d_in[0];
    const float* att    = (const float*)d_in[1];
    const float* prev_c = (const float*)d_in[2];
    const float* prev_h = (const float*)d_in[3];
    const float* a2a_w  = (const float*)d_in[4];
    const float* a2a_b  = (const float*)d_in[5];
    const float* h2a_w  = (const float*)d_in[6];
    const float* h2a_b  = (const float*)d_in[7];
    const float* d2d_w  = (const float*)d_in[8];
    const float* d2d_b  = (const float*)d_in[9];
    const float* i2h_w  = (const float*)d_in[10];
    const float* i2h_b  = (const float*)d_in[11];
    const float* h2h_w  = (const float*)d_in[12];
    const float* h2h_b  = (const float*)d_in[13];
    const float* r2a_w  = (const float*)d_in[14];
    const float* r2a_b  = (const float*)d_in[15];
    const float* proj_w = (const float*)d_in[16];
    const float* proj_b = (const float*)d_in[17];

    float* ws      = (float*)d_ws;
    float* att_h   = ws + OFF_ATTH;
    float* score   = ws + OFF_SCORE;
    float* weight  = ws + OFF_WEIGHT;
    float* att_res = ws + OFF_ATTRES;
    float* P0      = ws + OFF_P0;
    float* P1      = ws + OFF_P1;
    float* P2      = ws + OFF_P2;
    __bf16* nh_bf  = (__bf16*)(ws + OFF_NHBF);
    float* logits  = ws + OFF_LOGITS;
    __bf16* packA  = (__bf16*)(ws + OFF_PACKA);
    __bf16* packH  = (__bf16*)(ws + OFF_PACKH);
    __bf16* packP  = (__bf16*)(ws + OFF_PACKP);
    float* out     = (float*)d_out;

    hipMemsetAsync(att_res, 0, B_ * R_ * sizeof(float), stream);
    pack_kernel<<<10512, 256, 0, stream>>>(a2a_w, h2a_w, proj_w, packA, packH, packP);
    att_h_gemm<<<dim3(B_ / 64, 4), 256, 0, stream>>>(prev_h, packH, h2a_b, att_h);
    score_gemm_mfma<<<M_ / 64, 256, 0, stream>>>(att, packA, a2a_b, d2d_w, att_h, score);
    softmax_kernel<<<B_, 256, 0, stream>>>(score, d2d_b, weight);
    att_res_kernel<<<dim3(B_, 4), 256, 0, stream>>>(att, weight, att_res);
    sums_gemm_mfma<<<dim3(B_ / 64, G4 / 64, 3), 256, 0, stream>>>(
        x, prev_h, att_res, i2h_w, h2h_w, r2a_w, P0, P1, P2);
    gates_kernel<<<(B_ * R_) / 256, 256, 0, stream>>>(
        P0, P1, P2, i2h_b, h2h_b, r2a_b, prev_c, out, out + B_ * R_, nh_bf);
    proj_gemm_mfma<<<dim3(B_ / 64, (V_ + 63) / 64), 256, 0, stream>>>(
        nh_bf, packP, proj_b, logits);
    logsoftmax_kernel<<<B_, 1024, 0, stream>>>(logits, out + 2 * B_ * R_);
}

// Round 5
// 637.050 us; speedup vs baseline: 1.1279x; 1.1279x over previous
//
#include <hip/hip_runtime.h>
#include <math.h>

#define B_ 256
#define A_ 196
#define R_ 1024
#define V_ 10000
#define G4 4096
#define M_ (B_ * A_)   // 50176

typedef __bf16 bf16x8 __attribute__((ext_vector_type(8)));
typedef float f32x4 __attribute__((ext_vector_type(4)));

// ws layout in floats (~26 MB)
#define OFF_ATTH   0
#define OFF_SCORE  50176
#define OFF_WEIGHT 100352
#define OFF_ATTRES 150528
#define OFF_P0     412672
#define OFF_P1     1461248
#define OFF_P2     2509824
#define OFF_NHBF   3558400
#define OFF_LOGITS 3689472
#define OFF_PACKA  6261760   // a2a_w bf16 [224][1024] (zero-padded rows 196..223)
#define OFF_PACKH  6376448   // h2a_w bf16 [256][1024]

__device__ __forceinline__ float tanh_fast(float x) {
    float e = __expf(2.f * x);
    return 1.f - 2.f / (e + 1.f);
}
__device__ __forceinline__ float sigmoid_fast(float x) {
    return 1.f / (1.f + __expf(-x));
}

__device__ __forceinline__ bf16x8 cvt8(float4 f0, float4 f1) {
    bf16x8 v;
    v[0] = (__bf16)f0.x; v[1] = (__bf16)f0.y; v[2] = (__bf16)f0.z; v[3] = (__bf16)f0.w;
    v[4] = (__bf16)f1.x; v[5] = (__bf16)f1.y; v[6] = (__bf16)f1.z; v[7] = (__bf16)f1.w;
    return v;
}

// ---------------- kernel 0: pack a2a_w (224 rows) + h2a_w (256 rows) to bf16 --
__global__ void pack_kernel(const float* __restrict__ a2a_w,
                            const float* __restrict__ h2a_w,
                            __bf16* __restrict__ packA,   // [224][1024]
                            __bf16* __restrict__ packH) { // [256][1024]
    int row = blockIdx.x;
    int c = threadIdx.x * 4;
    const float* src;
    __bf16* dst;
    if (row < 224) {
        src = (row < A_) ? a2a_w + (size_t)row * R_ + c : nullptr;
        dst = packA + (size_t)row * R_ + c;
    } else {
        int r2 = row - 224;
        src = (r2 < A_) ? h2a_w + (size_t)r2 * R_ + c : nullptr;
        dst = packH + (size_t)r2 * R_ + c;
    }
    float4 f = src ? *(const float4*)src : make_float4(0.f, 0.f, 0.f, 0.f);
    dst[0] = (__bf16)f.x; dst[1] = (__bf16)f.y; dst[2] = (__bf16)f.z; dst[3] = (__bf16)f.w;
}

// ---------------- kernel 1: att_h = prev_h @ h2a_w.T + h2a_b  (MFMA) ----------
__global__ __launch_bounds__(256)
void att_h_gemm(const float* __restrict__ prev_h,
                const __bf16* __restrict__ packH,
                const float* __restrict__ h2a_b,
                float* __restrict__ att_h) {
    __shared__ alignas(16) __bf16 As[64][40];
    __shared__ alignas(16) __bf16 Bs[64][40];
    int tid = threadIdx.x;
    int m0 = blockIdx.x * 64, n0 = blockIdx.y * 64;
    int lane = tid & 63, w = tid >> 6, ln = lane & 15, quad = lane >> 4;
    int arow = tid >> 2, akq = (tid & 3) * 8;

    f32x4 acc[4];
#pragma unroll
    for (int t = 0; t < 4; ++t) acc[t] = {0.f, 0.f, 0.f, 0.f};

    const float* Asrc = prev_h + (size_t)(m0 + arow) * R_ + akq;
    const __bf16* Bsrc = packH + (size_t)(n0 + arow) * R_ + akq;

    float4 pa0 = *(const float4*)Asrc;
    float4 pa1 = *(const float4*)(Asrc + 4);
    bf16x8 pb = *(const bf16x8*)Bsrc;

    for (int k0 = 0; k0 < R_; k0 += 32) {
        __syncthreads();
        *(bf16x8*)&As[arow][akq] = cvt8(pa0, pa1);
        *(bf16x8*)&Bs[arow][akq] = pb;
        __syncthreads();
        if (k0 + 32 < R_) {
            pa0 = *(const float4*)(Asrc + k0 + 32);
            pa1 = *(const float4*)(Asrc + k0 + 36);
            pb = *(const bf16x8*)(Bsrc + k0 + 32);
        }
        bf16x8 a = *(bf16x8*)&As[w * 16 + ln][quad * 8];
#pragma unroll
        for (int t = 0; t < 4; ++t) {
            bf16x8 b = *(bf16x8*)&Bs[t * 16 + ln][quad * 8];
            acc[t] = __builtin_amdgcn_mfma_f32_16x16x32_bf16(a, b, acc[t], 0, 0, 0);
        }
    }
#pragma unroll
    for (int t = 0; t < 4; ++t) {
#pragma unroll
        for (int r = 0; r < 4; ++r) {
            int m = m0 + w * 16 + quad * 4 + r;
            int n = n0 + t * 16 + ln;
            if (n < A_) att_h[m * A_ + n] = acc[t][r] + h2a_b[n];
        }
    }
}

// ---------------- kernel 2: attention GEMM (MFMA) + tanh/d2d epilogue ---------
// BM=32, grid 1568 blocks. N padded to 224 = 14 tiles; waves {0,2} take tiles
// 0..6, waves {1,3} tiles 7..13; waves {0,1} rows 0..15, {2,3} rows 16..31.
// acc = 7 f32x4 = 28 VGPRs (uniform, no spill). A depth-2 prefetch, B depth-1.
__global__ __launch_bounds__(256)
void score_gemm_mfma(const float* __restrict__ att,
                     const __bf16* __restrict__ packA,   // [224][1024]
                     const float* __restrict__ a2a_b,
                     const float* __restrict__ d2d_w,
                     const float* __restrict__ att_h,
                     float* __restrict__ score) {
    __shared__ alignas(16) __bf16 As[32][40];
    __shared__ alignas(16) __bf16 Bs[224][40];
    __shared__ float sred[4][16];
    int tid = threadIdx.x;
    int m0 = blockIdx.x * 32;
    int lane = tid & 63, w = tid >> 6, ln = lane & 15, quad = lane >> 4;
    int nbase = (w & 1) * 7;     // n-tile start for this wave
    int rbase = (w >> 1) * 16;   // row start for this wave

    f32x4 acc[7];
#pragma unroll
    for (int t = 0; t < 7; ++t) acc[t] = {0.f, 0.f, 0.f, 0.f};

    // staging roles: tid<128 -> 4 B-chunks; tid>=128 -> 3 B-chunks + 1 A-chunk
    bool isA = tid >= 128;
    int arow = (tid - 128) >> 2;
    int akq = ((tid - 128) & 3) * 8;
    const float* Asrc = att + (size_t)(m0 + (isA ? arow : 0)) * R_ + akq;

    float4 pa0[2], pa1[2];
    if (isA) {
        pa0[0] = *(const float4*)(Asrc);      pa1[0] = *(const float4*)(Asrc + 4);
        pa0[1] = *(const float4*)(Asrc + 32); pa1[1] = *(const float4*)(Asrc + 36);
    }
    bf16x8 pbv[4];
#pragma unroll
    for (int i = 0; i < 4; ++i) {
        int c = tid + i * 256;
        if (c < 896) {
            int brow = c >> 2, bkq = (c & 3) * 8;
            pbv[i] = *(const bf16x8*)(packA + (size_t)brow * R_ + bkq);
        }
    }

    for (int it = 0; it < 32; ++it) {
        int k0 = it * 32;
        int p = it & 1;
        __syncthreads();
#pragma unroll
        for (int i = 0; i < 4; ++i) {
            int c = tid + i * 256;
            if (c < 896) {
                int brow = c >> 2, bkq = (c & 3) * 8;
                *(bf16x8*)&Bs[brow][bkq] = pbv[i];
            }
        }
        if (isA) *(bf16x8*)&As[arow][akq] = cvt8(pa0[p], pa1[p]);
        __syncthreads();
        if (isA && k0 + 64 < R_) {
            pa0[p] = *(const float4*)(Asrc + k0 + 64);
            pa1[p] = *(const float4*)(Asrc + k0 + 68);
        }
        if (k0 + 32 < R_) {
#pragma unroll
            for (int i = 0; i < 4; ++i) {
                int c = tid + i * 256;
                if (c < 896) {
                    int brow = c >> 2, bkq = (c & 3) * 8;
                    pbv[i] = *(const bf16x8*)(packA + (size_t)brow * R_ + k0 + 32 + bkq);
                }
            }
        }
        bf16x8 a = *(bf16x8*)&As[rbase + ln][quad * 8];
#pragma unroll
        for (int t = 0; t < 7; ++t) {
            bf16x8 b = *(bf16x8*)&Bs[(nbase + t) * 16 + ln][quad * 8];
            acc[t] = __builtin_amdgcn_mfma_f32_16x16x32_bf16(a, b, acc[t], 0, 0, 0);
        }
    }

    float wv[7], bb[7];
#pragma unroll
    for (int t = 0; t < 7; ++t) {
        int n = (nbase + t) * 16 + ln;
        bool v = n < A_;
        wv[t] = v ? d2d_w[n] : 0.f;
        bb[t] = v ? a2a_b[n] : 0.f;
    }
#pragma unroll
    for (int r = 0; r < 4; ++r) {
        int lrow = quad * 4 + r;
        float ah = att_h[m0 + rbase + lrow];
        float pp = 0.f;
#pragma unroll
        for (int t = 0; t < 7; ++t)
            pp += tanh_fast(acc[t][r] + bb[t] + ah) * wv[t];
        pp += __shfl_xor(pp, 1);
        pp += __shfl_xor(pp, 2);
        pp += __shfl_xor(pp, 4);
        pp += __shfl_xor(pp, 8);
        if (ln == 0) sred[w][lrow] = pp;
    }
    __syncthreads();
    if (tid < 32) {
        float v = (tid < 16) ? (sred[0][tid] + sred[1][tid])
                             : (sred[2][tid - 16] + sred[3][tid - 16]);
        score[m0 + tid] = v;
    }
}

// ---------------- kernel 3: softmax over i per batch ---------------------------
__global__ void softmax_kernel(const float* __restrict__ score,
                               const float* __restrict__ d2d_b,
                               float* __restrict__ weight) {
    int b = blockIdx.x;
    int i = threadIdx.x;
    __shared__ float red[256];
    float sval = 0.f;
    float s = -1e30f;
    if (i < A_) {
        sval = score[b * A_ + i] + d2d_b[0];
        s = sval;
    }
    red[i] = s; __syncthreads();
    for (int off = 128; off > 0; off >>= 1) {
        if (i < off) red[i] = fmaxf(red[i], red[i + off]);
        __syncthreads();
    }
    float mx = red[0]; __syncthreads();
    float e = (i < A_) ? __expf(sval - mx) : 0.f;
    red[i] = e; __syncthreads();
    for (int off = 128; off > 0; off >>= 1) {
        if (i < off) red[i] += red[i + off];
        __syncthreads();
    }
    float inv = 1.f / red[0];
    if (i < A_) weight[b * A_ + i] = e * inv;
}

// ---------------- kernel 4: att_res += partial over i-quarter (atomic) --------
__global__ __launch_bounds__(256)
void att_res_kernel(const float* __restrict__ att,
                    const float* __restrict__ weight,
                    float* __restrict__ att_res) {
    int b = blockIdx.x;
    int seg = blockIdx.y;          // 4 segments of 49 rows
    int r = threadIdx.x * 4;
    __shared__ float w[49];
    int i0 = seg * 49;
    if (threadIdx.x < 49) w[threadIdx.x] = weight[b * A_ + i0 + threadIdx.x];
    __syncthreads();
    const float* ap = att + ((size_t)b * A_ + i0) * R_ + r;
    float4 acc = make_float4(0.f, 0.f, 0.f, 0.f);
    for (int i = 0; i < 49; i += 7) {
#pragma unroll
        for (int j = 0; j < 7; ++j) {
            float4 v = *(const float4*)(ap + (size_t)(i + j) * R_);
            float ww = w[i + j];
            acc.x += v.x * ww; acc.y += v.y * ww;
            acc.z += v.z * ww; acc.w += v.w * ww;
        }
    }
    float* dst = att_res + (size_t)b * R_ + r;
    atomicAdd(dst + 0, acc.x);
    atomicAdd(dst + 1, acc.y);
    atomicAdd(dst + 2, acc.z);
    atomicAdd(dst + 3, acc.w);
}

// ---------------- kernel 5: sums GEMM (MFMA, phase-split z=3) ------------------
__global__ __launch_bounds__(256)
void sums_gemm_mfma(const float* __restrict__ x,
                    const float* __restrict__ prev_h,
                    const float* __restrict__ att_res,
                    const float* __restrict__ i2h_w,
                    const float* __restrict__ h2h_w,
                    const float* __restrict__ r2a_w,
                    float* __restrict__ P0,
                    float* __restrict__ P1,
                    float* __restrict__ P2) {
    __shared__ alignas(16) __bf16 As[64][40];
    __shared__ alignas(16) __bf16 Bs[64][40];
    int tid = threadIdx.x;
    int m0 = blockIdx.x * 64, n0 = blockIdx.y * 64;
    int z = blockIdx.z;
    int lane = tid & 63, w = tid >> 6, ln = lane & 15, quad = lane >> 4;
    int arow = tid >> 2, akq = (tid & 3) * 8;

    f32x4 acc[4];
#pragma unroll
    for (int t = 0; t < 4; ++t) acc[t] = {0.f, 0.f, 0.f, 0.f};

    const float* Al[3] = {x, prev_h, att_res};
    const float* Bl[3] = {i2h_w, h2h_w, r2a_w};
    float* Pl[3] = {P0, P1, P2};
    const float* Asrc = Al[z] + (size_t)(m0 + arow) * R_ + akq;
    const float* Bsrc = Bl[z] + (size_t)(n0 + arow) * R_ + akq;

    float4 pa0 = *(const float4*)Asrc;
    float4 pa1 = *(const float4*)(Asrc + 4);
    float4 pb0 = *(const float4*)Bsrc;
    float4 pb1 = *(const float4*)(Bsrc + 4);
    for (int k0 = 0; k0 < R_; k0 += 32) {
        __syncthreads();
        *(bf16x8*)&As[arow][akq] = cvt8(pa0, pa1);
        *(bf16x8*)&Bs[arow][akq] = cvt8(pb0, pb1);
        __syncthreads();
        if (k0 + 32 < R_) {
            pa0 = *(const float4*)(Asrc + k0 + 32);
            pa1 = *(const float4*)(Asrc + k0 + 36);
            pb0 = *(const float4*)(Bsrc + k0 + 32);
            pb1 = *(const float4*)(Bsrc + k0 + 36);
        }
        bf16x8 a = *(bf16x8*)&As[w * 16 + ln][quad * 8];
#pragma unroll
        for (int t = 0; t < 4; ++t) {
            bf16x8 b = *(bf16x8*)&Bs[t * 16 + ln][quad * 8];
            acc[t] = __builtin_amdgcn_mfma_f32_16x16x32_bf16(a, b, acc[t], 0, 0, 0);
        }
    }
    float* P = Pl[z];
#pragma unroll
    for (int t = 0; t < 4; ++t) {
#pragma unroll
        for (int r = 0; r < 4; ++r) {
            int m = m0 + w * 16 + quad * 4 + r;
            int n = n0 + t * 16 + ln;
            P[(size_t)m * G4 + n] = acc[t][r];
        }
    }
}

// ---------------- kernel 6: LSTM gates ----------------------------------------
__global__ void gates_kernel(const float* __restrict__ P0,
                             const float* __restrict__ P1,
                             const float* __restrict__ P2,
                             const float* __restrict__ i2h_b,
                             const float* __restrict__ h2h_b,
                             const float* __restrict__ r2a_b,
                             const float* __restrict__ prev_c,
                             float* __restrict__ out_c,
                             float* __restrict__ out_h,
                             __bf16* __restrict__ nh_bf) {
    int idx = blockIdx.x * 256 + threadIdx.x;
    int b = idx >> 10, r = idx & 1023;
    size_t off = (size_t)b * G4;
    float s0 = P0[off + r] + P1[off + r] + P2[off + r]
             + i2h_b[r] + h2h_b[r] + r2a_b[r];
    float s1 = P0[off + R_ + r] + P1[off + R_ + r] + P2[off + R_ + r]
             + i2h_b[R_ + r] + h2h_b[R_ + r] + r2a_b[R_ + r];
    float s2 = P0[off + 2 * R_ + r] + P1[off + 2 * R_ + r] + P2[off + 2 * R_ + r]
             + i2h_b[2 * R_ + r] + h2h_b[2 * R_ + r] + r2a_b[2 * R_ + r];
    float s3 = P0[off + 3 * R_ + r] + P1[off + 3 * R_ + r] + P2[off + 3 * R_ + r]
             + i2h_b[3 * R_ + r] + h2h_b[3 * R_ + r] + r2a_b[3 * R_ + r];
    float ig = sigmoid_fast(s0);
    float fg = sigmoid_fast(s1);
    float og = sigmoid_fast(s2);
    float it = tanh_fast(s3);
    float nc = fg * prev_c[idx] + ig * it;
    float nh = og * tanh_fast(nc);
    out_c[idx] = nc;
    out_h[idx] = nh;
    nh_bf[idx] = (__bf16)nh;
}

// ---------------- kernel 7: proj GEMM (MFMA, fp32 B cvt in-loop) ---------------
__global__ __launch_bounds__(256)
void proj_gemm_mfma(const __bf16* __restrict__ nh_bf,
                    const float* __restrict__ proj_w,
                    const float* __restrict__ proj_b,
                    float* __restrict__ logits) {
    __shared__ alignas(16) __bf16 As[64][40];
    __shared__ alignas(16) __bf16 Bs[64][40];
    int tid = threadIdx.x;
    int m0 = blockIdx.x * 64, n0 = blockIdx.y * 64;
    int lane = tid & 63, w = tid >> 6, ln = lane & 15, quad = lane >> 4;
    int arow = tid >> 2, akq = (tid & 3) * 8;

    f32x4 acc[4];
#pragma unroll
    for (int t = 0; t < 4; ++t) acc[t] = {0.f, 0.f, 0.f, 0.f};

    int nr = n0 + arow;
    int nrc = nr < V_ ? nr : V_ - 1;
    const __bf16* Asrc = nh_bf + (size_t)(m0 + arow) * R_ + akq;
    const float* Bsrc = proj_w + (size_t)nrc * R_ + akq;

    bf16x8 pa = *(const bf16x8*)Asrc;
    float4 pb0 = *(const float4*)Bsrc;
    float4 pb1 = *(const float4*)(Bsrc + 4);

    for (int k0 = 0; k0 < R_; k0 += 32) {
        __syncthreads();
        *(bf16x8*)&As[arow][akq] = pa;
        *(bf16x8*)&Bs[arow][akq] = cvt8(pb0, pb1);
        __syncthreads();
        if (k0 + 32 < R_) {
            pa = *(const bf16x8*)(Asrc + k0 + 32);
            pb0 = *(const float4*)(Bsrc + k0 + 32);
            pb1 = *(const float4*)(Bsrc + k0 + 36);
        }
        bf16x8 a = *(bf16x8*)&As[w * 16 + ln][quad * 8];
#pragma unroll
        for (int t = 0; t < 4; ++t) {
            bf16x8 b = *(bf16x8*)&Bs[t * 16 + ln][quad * 8];
            acc[t] = __builtin_amdgcn_mfma_f32_16x16x32_bf16(a, b, acc[t], 0, 0, 0);
        }
    }
#pragma unroll
    for (int t = 0; t < 4; ++t) {
#pragma unroll
        for (int r = 0; r < 4; ++r) {
            int m = m0 + w * 16 + quad * 4 + r;
            int n = n0 + t * 16 + ln;
            if (n < V_) logits[(size_t)m * V_ + n] = acc[t][r] + proj_b[n];
        }
    }
}

// ---------------- kernel 8: log_softmax over V per row (1024 threads) ----------
__global__ __launch_bounds__(1024)
void logsoftmax_kernel(const float* __restrict__ logits,
                       float* __restrict__ out) {
    int b = blockIdx.x, t = threadIdx.x;
    __shared__ float red[1024];
    const float* lp = logits + (size_t)b * V_;
    float mx = -1e30f;
    for (int v = t; v < V_; v += 1024) mx = fmaxf(mx, lp[v]);
    red[t] = mx; __syncthreads();
    for (int off = 512; off > 0; off >>= 1) {
        if (t < off) red[t] = fmaxf(red[t], red[t + off]);
        __syncthreads();
    }
    mx = red[0]; __syncthreads();
    float s = 0.f;
    for (int v = t; v < V_; v += 1024) s += __expf(lp[v] - mx);
    red[t] = s; __syncthreads();
    for (int off = 512; off > 0; off >>= 1) {
        if (t < off) red[t] += red[t + off];
        __syncthreads();
    }
    float lse = mx + __logf(red[0]);
    float* op = out + (size_t)b * V_;
    for (int v = t; v < V_; v += 1024) op[v] = lp[v] - lse;
}

extern "C" void kernel_launch(void* const* d_in, const int* in_sizes, int n_in,
                              void* d_out, int out_size, void* d_ws, size_t ws_size,
                              hipStream_t stream) {
    const float* x      = (const float*)d_in[0];
    const float* att    = (const float*)d_in[1];
    const float* prev_c = (const float*)d_in[2];
    const float* prev_h = (const float*)d_in[3];
    const float* a2a_w  = (const float*)d_in[4];
    const float* a2a_b  = (const float*)d_in[5];
    const float* h2a_w  = (const float*)d_in[6];
    const float* h2a_b  = (const float*)d_in[7];
    const float* d2d_w  = (const float*)d_in[8];
    const float* d2d_b  = (const float*)d_in[9];
    const float* i2h_w  = (const float*)d_in[10];
    const float* i2h_b  = (const float*)d_in[11];
    const float* h2h_w  = (const float*)d_in[12];
    const float* h2h_b  = (const float*)d_in[13];
    const float* r2a_w  = (const float*)d_in[14];
    const float* r2a_b  = (const float*)d_in[15];
    const float* proj_w = (const float*)d_in[16];
    const float* proj_b = (const float*)d_in[17];

    float* ws      = (float*)d_ws;
    float* att_h   = ws + OFF_ATTH;
    float* score   = ws + OFF_SCORE;
    float* weight  = ws + OFF_WEIGHT;
    float* att_res = ws + OFF_ATTRES;
    float* P0      = ws + OFF_P0;
    float* P1      = ws + OFF_P1;
    float* P2      = ws + OFF_P2;
    __bf16* nh_bf  = (__bf16*)(ws + OFF_NHBF);
    float* logits  = ws + OFF_LOGITS;
    __bf16* packA  = (__bf16*)(ws + OFF_PACKA);
    __bf16* packH  = (__bf16*)(ws + OFF_PACKH);
    float* out     = (float*)d_out;

    hipMemsetAsync(att_res, 0, B_ * R_ * sizeof(float), stream);
    pack_kernel<<<480, 256, 0, stream>>>(a2a_w, h2a_w, packA, packH);
    att_h_gemm<<<dim3(B_ / 64, 4), 256, 0, stream>>>(prev_h, packH, h2a_b, att_h);
    score_gemm_mfma<<<M_ / 32, 256, 0, stream>>>(att, packA, a2a_b, d2d_w, att_h, score);
    softmax_kernel<<<B_, 256, 0, stream>>>(score, d2d_b, weight);
    att_res_kernel<<<dim3(B_, 4), 256, 0, stream>>>(att, weight, att_res);
    sums_gemm_mfma<<<dim3(B_ / 64, G4 / 64, 3), 256, 0, stream>>>(
        x, prev_h, att_res, i2h_w, h2h_w, r2a_w, P0, P1, P2);
    gates_kernel<<<(B_ * R_) / 256, 256, 0, stream>>>(
        P0, P1, P2, i2h_b, h2h_b, r2a_b, prev_c, out, out + B_ * R_, nh_bf);
    proj_gemm_mfma<<<dim3(B_ / 64, (V_ + 63) / 64), 256, 0, stream>>>(
        nh_bf, proj_w, proj_b, logits);
    logsoftmax_kernel<<<B_, 1024, 0, stream>>>(logits, out + 2 * B_ * R_);
}